// Round 9
// baseline (1727.125 us; speedup 1.0000x reference)
//
#include <hip/hip_runtime.h>
#include <cstdint>

// Problem constants: B=32, C=1, H=W=512, 200 iters, top-100
#define IW 512
#define IH 512
#define HW 262144
#define NIMG 32
#define MAXD 100
// Propagation: 128x40 tile (2 cols/lane), halo 8, core 112x24, 25 passes x 8 iters
#define TH 40
#define HALO 8
#define CX 112
#define CY 24
#define NPASS 25
#define NTX 5              // ceil(512/112)
#define NTY 22             // ceil(512/24)
#define GH 8192            // global hash slots per image (distinct labels ~1-2K)
#define SLOTS 2048         // LDS hash slots per stat block
#define DCAP 8192          // dense-list capacity per image
#define CAP 8192           // topk LDS key-array capacity (64KB)

// ---------------- workspace layout (bytes) ----------------
// [0, 32MB)  labA during prop. AFTER prop (labels live in labB):
//   gk    @ 0    1MB  label keys                (memset 0)
//   gcnt  @ 1MB  1MB  counts                    (memset 0)
//   gx1   @ 2MB  1MB  xmax                      (memset 0)
//   gy1   @ 3MB  1MB  ymax                      (memset 0)
//   gx0r  @ 4MB  1MB  max(511-x) -> xmin        (memset 0)
//   gy0r  @ 5MB  1MB  max(511-y) -> ymin        (memset 0)
//   dcount@ 6MB  4KB                            (memset 0)  [one 6MB+4K memset]
//   dlist @ 6MB+4K  1MB  dense slot list        (dcount-guarded)
//   small @ 8MB  rank_count, rank_slot
// [33554688, ..) labB (final labels; NPASS=25 odd)
#define OFF_LABB  33554688ull
#define OFF_DLIST 6295552ull
#define OFF_SMALL 8388608ull

__device__ __forceinline__ int imax3(int a, int b, int c) {
    int m = a > b ? a : b;
    return m > c ? m : c;
}
__device__ __forceinline__ unsigned umin2(unsigned a, unsigned b) { return a < b ? a : b; }
__device__ __forceinline__ unsigned umax2(unsigned a, unsigned b) { return a > b ? a : b; }

// ---------------- 1. init labels: lab = fg ? (pixelIdx+1) : 0 ----------------
__global__ __launch_bounds__(256) void init_labels(const float4* __restrict__ img,
                                                   int4* __restrict__ lab) {
    const size_t n = (size_t)NIMG * HW / 4;
    const size_t stride = (size_t)gridDim.x * 256;
    for (size_t i = (size_t)blockIdx.x * 256 + threadIdx.x; i < n; i += stride) {
        float4 f = img[i];
        int p = (int)((i * 4) & (HW - 1));   // pixel index within image (HW%4==0)
        int4 o;
        o.x = (f.x > 127.5f) ? p + 1 : 0;    // x/255>0.5 <=> x>127.5 (ints 0..255)
        o.y = (f.y > 127.5f) ? p + 2 : 0;
        o.z = (f.z > 127.5f) ? p + 3 : 0;
        o.w = (f.w > 127.5f) ? p + 4 : 0;
        lab[i] = o;
    }
}

// ---------------- 2. propagation: 8 masked maxpool iters per pass ------------
// 1 wave per 128x40 tile; lane L owns columns x0+2L (a[]) and x0+2L+1 (b[]).
// TH 48->40: 3520 waves/pass (3.4/SIMD, was 2.5) to test the latency-bound
// hypothesis; +11% halo compute. Edge garbage absorbed by 8-wide halo;
// core = local cols 8..119 (lanes 4..59), rows 8..31.
// mask == (v != 0): fg labels monotone >=1, bg stays 0; OOB = 0 matches the
// reference's reduce_window init=0 padding.
__global__ __launch_bounds__(64) void prop_pass(const int* __restrict__ in,
                                                int* __restrict__ out) {
    const int img = blockIdx.z;
    const int x0 = blockIdx.x * CX - HALO;       // even
    const int y0 = blockIdx.y * CY - HALO;
    const int lane = threadIdx.x;
    const int xe = x0 + 2 * lane;                // even column of this lane
    const bool colok = (xe >= 0) && (xe < IW);   // pair fully in or fully out
    const int2* __restrict__ ip2 = (const int2*)(in + (size_t)img * HW);
    int2* __restrict__ op2 = (int2*)(out + (size_t)img * HW);

    int a[TH], b[TH];
#pragma unroll
    for (int i = 0; i < TH; ++i) {
        int gy = y0 + i;
        int2 ld = make_int2(0, 0);
        if (colok && gy >= 0 && gy < IH) ld = ip2[gy * (IW / 2) + (xe >> 1)];
        a[i] = ld.x; b[i] = ld.y;
    }

#pragma unroll 1
    for (int it = 0; it < HALO; ++it) {
        int la0 = __shfl_up(b[0], 1, 64);
        int ra0 = __shfl_down(a[0], 1, 64);
        int haP = 0, hbP = 0;
        int haC = imax3(la0, a[0], b[0]);
        int hbC = imax3(a[0], b[0], ra0);
#pragma unroll
        for (int i = 0; i < TH; ++i) {
            int haN = 0, hbN = 0;
            if (i < TH - 1) {
                int l = __shfl_up(b[i + 1], 1, 64);
                int r = __shfl_down(a[i + 1], 1, 64);
                haN = imax3(l, a[i + 1], b[i + 1]);
                hbN = imax3(a[i + 1], b[i + 1], r);
            }
            int na = imax3(haP, haC, haN);
            int nb = imax3(hbP, hbC, hbN);
            a[i] = (a[i] == 0) ? 0 : na;
            b[i] = (b[i] == 0) ? 0 : nb;
            haP = haC; haC = haN; hbP = hbC; hbC = hbN;
        }
    }

    // write 112x24 core (lanes 4..59 = local cols 8..119, rows 8..31)
    if (lane >= 4 && lane < 60 && colok) {
#pragma unroll
        for (int i = HALO; i < TH - HALO; ++i) {
            int gy = y0 + i;                      // >= 0 since i >= 8
            if (gy < IH) op2[gy * (IW / 2) + (xe >> 1)] = make_int2(a[i], b[i]);
        }
    }
}

// -------- global hash find-or-insert; NEW keys append their slot to dlist ----
__device__ __forceinline__ unsigned gfind_ins(unsigned* __restrict__ gk, unsigned key,
                                              unsigned* __restrict__ dlist,
                                              unsigned* __restrict__ dcount) {
    unsigned h = (key * 2654435761u) >> 19;      // top 13 bits
    for (unsigned pr = 0; pr < GH; ++pr) {
        unsigned idx = (h + pr) & (GH - 1);
        unsigned k = gk[idx];
        if (k == key) return idx;
        if (k == 0u) {
            unsigned old = atomicCAS(&gk[idx], 0u, key);
            if (old == 0u) {
                unsigned pos = atomicAdd(dcount, 1u);
                if (pos < DCAP) dlist[pos] = idx;
                return idx;
            }
            if (old == key) return idx;
        }
    }
    return h;
}

// ---------------- 3. fused per-label stats with majority reduction -----------
// Round-8 counters: 5.6M LDS bank conflicts, 341us — nearly all fg belongs to
// one giant cluster, so per-pixel LDS atomics hit ONE address (~64-way
// serialized). Fix: (a) thread-local run merge of each int4 (adjacent fg px
// are ALWAYS same label); (b) runs matching the wave-majority label reduce in
// registers via shfl_xor butterfly -> 5 LDS atomics per WAVE; (c) minority
// runs use the scattered parallel path. Mins stored as max(511-v) so all
// arrays are memset-0.
__global__ __launch_bounds__(256) void stat_pass(const int* __restrict__ lab,
                                                 unsigned* __restrict__ gk,
                                                 unsigned* __restrict__ gcnt,
                                                 unsigned* __restrict__ gx0r,
                                                 unsigned* __restrict__ gx1,
                                                 unsigned* __restrict__ gy0r,
                                                 unsigned* __restrict__ gy1,
                                                 unsigned* __restrict__ dlist,
                                                 unsigned* __restrict__ dcount) {
    __shared__ unsigned hk[SLOTS], hc[SLOTS];
    __shared__ unsigned sx0r[SLOTS], sx1[SLOTS], sy0r[SLOTS], sy1[SLOTS];
    const int img = blockIdx.y;
    const int rb = blockIdx.x * 16;
    const int t = threadIdx.x;
    const int lane = t & 63;
    for (int i = t; i < SLOTS; i += 256) {
        hk[i] = 0; hc[i] = 0; sx0r[i] = 0; sx1[i] = 0; sy0r[i] = 0; sy1[i] = 0;
    }
    __syncthreads();
    unsigned* gki = gk + (size_t)img * GH;
    unsigned* gci = gcnt + (size_t)img * GH;
    unsigned* gx0i = gx0r + (size_t)img * GH;
    unsigned* gx1i = gx1 + (size_t)img * GH;
    unsigned* gy0i = gy0r + (size_t)img * GH;
    unsigned* gy1i = gy1 + (size_t)img * GH;
    unsigned* dli = dlist + (size_t)img * DCAP;
    unsigned* dci = dcount + img;

    // LDS hash update (or global fallback); mins in 511- form
    auto upd = [&](unsigned l, unsigned cnt, unsigned x0, unsigned x1, unsigned y) {
        unsigned h = (l * 2654435761u) >> 21;
        int idx = -1;
        for (int pr = 0; pr < 32; ++pr) {
            unsigned j = (h + pr) & (SLOTS - 1);
            unsigned k = hk[j];
            if (k == l) { idx = (int)j; break; }
            if (k == 0u) {
                unsigned old = atomicCAS(&hk[j], 0u, l);
                if (old == 0u || old == l) { idx = (int)j; break; }
            }
        }
        if (idx >= 0) {
            atomicAdd(&hc[idx], cnt);
            atomicMax(&sx0r[idx], 511u - x0); atomicMax(&sx1[idx], x1);
            atomicMax(&sy0r[idx], 511u - y);  atomicMax(&sy1[idx], y);
        } else {                                  // rare LDS overflow
            unsigned g = gfind_ins(gki, l, dli, dci);
            atomicAdd(&gci[g], cnt);
            atomicMax(&gx0i[g], 511u - x0); atomicMax(&gx1i[g], x1);
            atomicMax(&gy0i[g], 511u - y);  atomicMax(&gy1i[g], y);
        }
    };

    const int4* lp = (const int4*)(lab + (size_t)img * HW + rb * IW);
    for (int i = t; i < 16 * IW / 4; i += 256) {     // wave = half a row (y uniform)
        int4 v = lp[i];
        unsigned y = (unsigned)(rb + (i >> 7));
        unsigned xb = (unsigned)((i & 127) << 2);
        unsigned l0 = (unsigned)v.x, l1 = (unsigned)v.y,
                 l2 = (unsigned)v.z, l3 = (unsigned)v.w;
        unsigned rep = l0 ? l0 : (l1 ? l1 : (l2 ? l2 : l3));
        unsigned long long actm = __ballot(rep != 0u);
        if (actm == 0ull) continue;                  // wave-uniform: all bg
        int src = __ffsll((long long)actm) - 1;
        unsigned maj = (unsigned)__shfl((int)rep, src, 64);

        unsigned mcnt = 0, mx0 = 0xFFFFu, mx1 = 0;
#define EMIT(L, A, B)                                                          \
        if (L) {                                                               \
            if ((L) == maj) { mcnt += (B) - (A) + 1;                           \
                mx0 = umin2(mx0, xb + (A)); mx1 = umax2(mx1, xb + (B)); }      \
            else upd((L), (B) - (A) + 1, xb + (A), xb + (B), y);               \
        }
        unsigned cur = l0; unsigned rx0 = 0;
        if (l1 != cur) { EMIT(cur, rx0, 0u); cur = l1; rx0 = 1; }
        if (l2 != cur) { EMIT(cur, rx0, 1u); cur = l2; rx0 = 2; }
        if (l3 != cur) { EMIT(cur, rx0, 2u); cur = l3; rx0 = 3; }
        EMIT(cur, rx0, 3u);
#undef EMIT
        // wave-reduce majority stats (y uniform across wave)
        for (int s = 1; s < 64; s <<= 1) {
            mcnt += (unsigned)__shfl_xor((int)mcnt, s, 64);
            unsigned o0 = (unsigned)__shfl_xor((int)mx0, s, 64);
            unsigned o1 = (unsigned)__shfl_xor((int)mx1, s, 64);
            mx0 = umin2(mx0, o0); mx1 = umax2(mx1, o1);
        }
        if (lane == src && mcnt > 0) upd(maj, mcnt, mx0, mx1, y);
    }
    __syncthreads();
    for (int i = t; i < SLOTS; i += 256) {
        unsigned k = hk[i];
        if (!k) continue;
        unsigned g = gfind_ins(gki, k, dli, dci);
        atomicAdd(&gci[g], hc[i]);
        atomicMax(&gx0i[g], sx0r[i]); atomicMax(&gx1i[g], sx1[i]);
        atomicMax(&gy0i[g], sy0r[i]); atomicMax(&gy1i[g], sy1[i]);
    }
}

// ---------------- 4. exact top-100: dense-list load + cached-argmax ----------
// key = ((count<<19)|(HW-label))<<15 | slot  (count desc, label asc ==
// lax.top_k tie order; slot gathers bbox; keys unique).
__global__ __launch_bounds__(256) void topk(const unsigned* __restrict__ gk,
                                            const unsigned* __restrict__ gcnt,
                                            const unsigned* __restrict__ dlist,
                                            const unsigned* __restrict__ dcount,
                                            unsigned* __restrict__ rank_count,
                                            unsigned* __restrict__ rank_slot) {
    __shared__ unsigned long long keys[CAP];
    __shared__ unsigned long long wred[4];
    const int img = blockIdx.x;
    const int t = threadIdx.x;
    const int lane = t & 63, wid = t >> 6;
    for (int i = t; i < CAP; i += 256) keys[i] = 0;
    __syncthreads();

    unsigned nd = dcount[img];
    if (nd > CAP) nd = CAP;
    const unsigned* gki = gk + (size_t)img * GH;
    const unsigned* gci = gcnt + (size_t)img * GH;
    const unsigned* dli = dlist + (size_t)img * DCAP;
    for (unsigned i = t; i < nd; i += 256) {
        unsigned slot = dli[i];
        unsigned lb = gki[slot];
        unsigned c = gci[slot];
        keys[i] = ((((unsigned long long)c << 19) | (unsigned)(HW - lb)) << 15)
                  | slot;
    }
    __syncthreads();

    unsigned long long maxv = 0; int maxi = -1;
    for (int i = t; i < CAP; i += 256) {
        unsigned long long k = keys[i];
        if (k > maxv) { maxv = k; maxi = i; }
    }

    for (int r = 0; r < MAXD; ++r) {
        unsigned long long m = maxv;
        for (int s = 1; s < 64; s <<= 1) {
            unsigned long long o = (unsigned long long)__shfl_xor((long long)m, s, 64);
            if (o > m) m = o;
        }
        if (lane == 0) wred[wid] = m;
        __syncthreads();
        unsigned long long w = wred[0];
        if (wred[1] > w) w = wred[1];
        if (wred[2] > w) w = wred[2];
        if (wred[3] > w) w = wred[3];
        if (w != 0ull && maxv == w) {            // unique owner (keys unique)
            keys[maxi] = 0;
            rank_count[img * MAXD + r] = (unsigned)(w >> 34);
            rank_slot[img * MAXD + r]  = (unsigned)(w & 32767ull);
            maxv = 0; maxi = -1;
            for (int i = t; i < CAP; i += 256) {
                unsigned long long k = keys[i];
                if (k > maxv) { maxv = k; maxi = i; }
            }
        }
        if (w == 0ull && t == 0) {
            rank_count[img * MAXD + r] = 0;
            rank_slot[img * MAXD + r] = 0;
        }
        __syncthreads();
    }
}

// ---------------- 5. finalize: gather [xmin,ymin,xmax,ymax] or zeros ---------
__global__ __launch_bounds__(256) void final_out(const unsigned* __restrict__ rank_count,
                                                 const unsigned* __restrict__ rank_slot,
                                                 const unsigned* __restrict__ gx0r,
                                                 const unsigned* __restrict__ gx1,
                                                 const unsigned* __restrict__ gy0r,
                                                 const unsigned* __restrict__ gy1,
                                                 float* __restrict__ out) {
    int id = blockIdx.x * 256 + threadIdx.x;
    if (id >= NIMG * MAXD) return;
    unsigned c = rank_count[id];
    float4 b = make_float4(0.f, 0.f, 0.f, 0.f);
    if (c) {
        int img = id / MAXD;
        size_t g = (size_t)img * GH + rank_slot[id];
        b = make_float4((float)(511u - gx0r[g]), (float)(511u - gy0r[g]),
                        (float)gx1[g], (float)gy1[g]);
    }
    reinterpret_cast<float4*>(out)[id] = b;
}

// ---------------- launch ----------------
extern "C" void kernel_launch(void* const* d_in, const int* in_sizes, int n_in,
                              void* d_out, int out_size, void* d_ws, size_t ws_size,
                              hipStream_t stream) {
    (void)in_sizes; (void)n_in; (void)out_size; (void)ws_size;
    const float* img = (const float*)d_in[0];
    char* ws = (char*)d_ws;

    int* labA = (int*)ws;
    int* labB = (int*)(ws + OFF_LABB);
    // hash region aliases labA (dead after the last prop pass reads it)
    unsigned* gk   = (unsigned*)ws;                       // 0..1MB
    unsigned* gcnt = (unsigned*)(ws + 1048576ull);        // 1..2MB
    unsigned* gx1  = (unsigned*)(ws + 2097152ull);        // 2..3MB
    unsigned* gy1  = (unsigned*)(ws + 3145728ull);        // 3..4MB
    unsigned* gx0r = (unsigned*)(ws + 4194304ull);        // 4..5MB  max(511-x)
    unsigned* gy0r = (unsigned*)(ws + 5242880ull);        // 5..6MB  max(511-y)
    unsigned* dcount = (unsigned*)(ws + 6291456ull);      // 6MB..+4K
    unsigned* dlist = (unsigned*)(ws + OFF_DLIST);        // 1MB
    unsigned* rank_count = (unsigned*)(ws + OFF_SMALL);
    unsigned* rank_slot  = (unsigned*)(ws + OFF_SMALL + 16384ull);
    float* out = (float*)d_out;

    init_labels<<<2048, 256, 0, stream>>>((const float4*)img, (int4*)labA);

    // 25 passes x 8 iterations = exactly 200 masked maxpool iterations
    dim3 pg(NTX, NTY, NIMG);
    const int* pin = labA; int* pout = labB;
    for (int p = 0; p < NPASS; ++p) {
        prop_pass<<<pg, 64, 0, stream>>>(pin, pout);
        int* tmp = (int*)pin; pin = pout; pout = tmp;
    }
    // NPASS odd -> final labels in labB; labA region now free for the hash

    hipMemsetAsync(gk, 0, 6291456ull + 4096ull, stream);  // all hash arrays + dcount

    stat_pass<<<dim3(32, NIMG), 256, 0, stream>>>(pin, gk, gcnt, gx0r, gx1, gy0r, gy1,
                                                  dlist, dcount);
    topk<<<NIMG, 256, 0, stream>>>(gk, gcnt, dlist, dcount, rank_count, rank_slot);
    final_out<<<(NIMG * MAXD + 255) / 256, 256, 0, stream>>>(rank_count, rank_slot,
                                                             gx0r, gx1, gy0r, gy1, out);
}

// Round 10
// 1615.200 us; speedup vs baseline: 1.0693x; 1.0693x over previous
//
#include <hip/hip_runtime.h>
#include <cstdint>

// Problem constants: B=32, C=1, H=W=512, 200 iters, top-100
#define IW 512
#define IH 512
#define HW 262144
#define NIMG 32
#define MAXD 100
// Propagation: 128x64 tile (2 cols/lane), halo 10, core 108x44, 20 passes x 10 iters
#define TH 64
#define HALO 10
#define CX 108
#define CY 44
#define NPASS 20
#define NTX 5              // ceil(512/108)
#define NTY 12             // ceil(512/44)
#define GH 8192            // global hash slots per image (distinct labels ~1-2K)
#define SLOTS 2048         // LDS hash slots per stat block
#define DCAP 8192          // dense-list capacity per image
#define CAP 8192           // topk LDS key-array capacity (64KB)

// ---------------- workspace layout (bytes) ----------------
// [0, 32MB)        labA (final labels after EVEN pass count)
// [OFF_LABB, +32MB) labB during prop; AFTER prop (labels in labA) aliased as:
//   gk    @ +0    1MB  label keys           (memset 0)
//   gcnt  @ +1MB  1MB  counts               (memset 0)
//   gx1   @ +2MB  1MB  xmax                 (memset 0)
//   gy1   @ +3MB  1MB  ymax                 (memset 0)
//   gx0r  @ +4MB  1MB  max(511-x) -> xmin   (memset 0)
//   gy0r  @ +5MB  1MB  max(511-y) -> ymin   (memset 0)
//   dcount@ +6MB  4KB                       (memset 0)
//   dlist @ +6MB+4K 1MB dense slot list     (dcount-guarded)
//   rank  @ +8MB  rank_count, rank_slot
#define OFF_LABB  33554688ull

__device__ __forceinline__ int imax3(int a, int b, int c) {
    int m = a > b ? a : b;
    return m > c ? m : c;
}

// ---------------- 1. init labels: lab = fg ? (pixelIdx+1) : 0 ----------------
__global__ __launch_bounds__(256) void init_labels(const float4* __restrict__ img,
                                                   int4* __restrict__ lab) {
    const size_t n = (size_t)NIMG * HW / 4;
    const size_t stride = (size_t)gridDim.x * 256;
    for (size_t i = (size_t)blockIdx.x * 256 + threadIdx.x; i < n; i += stride) {
        float4 f = img[i];
        int p = (int)((i * 4) & (HW - 1));   // pixel index within image (HW%4==0)
        int4 o;
        o.x = (f.x > 127.5f) ? p + 1 : 0;    // x/255>0.5 <=> x>127.5 (ints 0..255)
        o.y = (f.y > 127.5f) ? p + 2 : 0;
        o.z = (f.z > 127.5f) ? p + 3 : 0;
        o.w = (f.w > 127.5f) ? p + 4 : 0;
        lab[i] = o;
    }
}

// ---------------- 2. propagation: 10 masked maxpool iters per pass -----------
// 1 wave per 128x64 tile; lane L owns columns x0+2L (a[]) and x0+2L+1 (b[]).
// Horizontal 3-max: col 2L needs (b[L-1], a[L], b[L]) -> 1 shfl_up(b);
//                   col 2L+1 needs (a[L], b[L], a[L+1]) -> 1 shfl_down(a).
// TH=64 reverted (cross-round totals: TH64=1267 < TH48=1413/1530 < TH40=1727
// — occupancy was NOT prop's limiter). HALO 8->10, 20 passes x 10 = 200 exact:
// -12% compute, -20% passes/memory/launches. Garbage advances <=1 px/iter from
// tile edge -> 10-wide halo absorbs it; core = local cols 10..117 (lanes
// 5..58), rows 10..53. mask == (v != 0); OOB = 0 matches reduce_window pad.
__global__ __launch_bounds__(64) void prop_pass(const int* __restrict__ in,
                                                int* __restrict__ out) {
    const int img = blockIdx.z;
    const int x0 = blockIdx.x * CX - HALO;       // even (CX, HALO even)
    const int y0 = blockIdx.y * CY - HALO;
    const int lane = threadIdx.x;
    const int xe = x0 + 2 * lane;                // even column of this lane
    const bool colok = (xe >= 0) && (xe < IW);   // pair fully in or fully out
    const int2* __restrict__ ip2 = (const int2*)(in + (size_t)img * HW);
    int2* __restrict__ op2 = (int2*)(out + (size_t)img * HW);

    int a[TH], b[TH];
#pragma unroll
    for (int i = 0; i < TH; ++i) {
        int gy = y0 + i;
        int2 ld = make_int2(0, 0);
        if (colok && gy >= 0 && gy < IH) ld = ip2[gy * (IW / 2) + (xe >> 1)];
        a[i] = ld.x; b[i] = ld.y;
    }

#pragma unroll 1
    for (int it = 0; it < HALO; ++it) {
        int la0 = __shfl_up(b[0], 1, 64);
        int ra0 = __shfl_down(a[0], 1, 64);
        int haP = 0, hbP = 0;
        int haC = imax3(la0, a[0], b[0]);
        int hbC = imax3(a[0], b[0], ra0);
#pragma unroll
        for (int i = 0; i < TH; ++i) {
            int haN = 0, hbN = 0;
            if (i < TH - 1) {
                int l = __shfl_up(b[i + 1], 1, 64);
                int r = __shfl_down(a[i + 1], 1, 64);
                haN = imax3(l, a[i + 1], b[i + 1]);
                hbN = imax3(a[i + 1], b[i + 1], r);
            }
            int na = imax3(haP, haC, haN);
            int nb = imax3(hbP, hbC, hbN);
            a[i] = (a[i] == 0) ? 0 : na;
            b[i] = (b[i] == 0) ? 0 : nb;
            haP = haC; haC = haN; hbP = hbC; hbC = hbN;
        }
    }

    // write 108x44 core (lanes 5..58 = local cols 10..117, rows 10..53)
    if (lane >= 5 && lane < 59 && colok) {
#pragma unroll
        for (int i = HALO; i < TH - HALO; ++i) {
            int gy = y0 + i;                      // >= 0 since i >= 10
            if (gy < IH) op2[gy * (IW / 2) + (xe >> 1)] = make_int2(a[i], b[i]);
        }
    }
}

// -------- global hash find-or-insert; NEW keys append their slot to dlist ----
__device__ __forceinline__ unsigned gfind_ins(unsigned* __restrict__ gk, unsigned key,
                                              unsigned* __restrict__ dlist,
                                              unsigned* __restrict__ dcount) {
    unsigned h = (key * 2654435761u) >> 19;      // top 13 bits
    for (unsigned pr = 0; pr < GH; ++pr) {
        unsigned idx = (h + pr) & (GH - 1);
        unsigned k = gk[idx];
        if (k == key) return idx;
        if (k == 0u) {
            unsigned old = atomicCAS(&gk[idx], 0u, key);
            if (old == 0u) {
                unsigned pos = atomicAdd(dcount, 1u);
                if (pos < DCAP) dlist[pos] = idx;
                return idx;
            }
            if (old == key) return idx;
        }
    }
    return h;
}

// ---------------- 3. per-label stats: thread-register run aggregation --------
// Round-9 majority-reduce REGRESSED (505us vs per-pixel 341us): the giant
// cluster is a patchwork of label-regions after 200 bounded iters, so wave
// majority captures little and the ballot/butterfly added overhead. Round-8
// per-pixel cost = LDS-atomic instruction count (5/px). Fix: thread owns 32
// CONSECUTIVE px of one row (8 int4, y uniform); accumulate (label,cnt,x0,x1)
// in REGISTERS, flush to LDS hash only on label change (~2-4 flushes/thread
// for coherent label fields; worst case = per-pixel). Mins stored as
// max(511-v) so all arrays memset-0.
__global__ __launch_bounds__(256) void stat_pass(const int* __restrict__ lab,
                                                 unsigned* __restrict__ gk,
                                                 unsigned* __restrict__ gcnt,
                                                 unsigned* __restrict__ gx0r,
                                                 unsigned* __restrict__ gx1,
                                                 unsigned* __restrict__ gy0r,
                                                 unsigned* __restrict__ gy1,
                                                 unsigned* __restrict__ dlist,
                                                 unsigned* __restrict__ dcount) {
    __shared__ unsigned hk[SLOTS], hc[SLOTS];
    __shared__ unsigned sx0r[SLOTS], sx1[SLOTS], sy0r[SLOTS], sy1[SLOTS];
    const int img = blockIdx.y;
    const int rb = blockIdx.x * 16;
    const int t = threadIdx.x;
    for (int i = t; i < SLOTS; i += 256) {
        hk[i] = 0; hc[i] = 0; sx0r[i] = 0; sx1[i] = 0; sy0r[i] = 0; sy1[i] = 0;
    }
    __syncthreads();
    unsigned* gki = gk + (size_t)img * GH;
    unsigned* gci = gcnt + (size_t)img * GH;
    unsigned* gx0i = gx0r + (size_t)img * GH;
    unsigned* gx1i = gx1 + (size_t)img * GH;
    unsigned* gy0i = gy0r + (size_t)img * GH;
    unsigned* gy1i = gy1 + (size_t)img * GH;
    unsigned* dli = dlist + (size_t)img * DCAP;
    unsigned* dci = dcount + img;

    const unsigned y = (unsigned)(rb + (t >> 4));      // thread's (uniform) row
    auto upd = [&](unsigned l, unsigned cnt, unsigned x0, unsigned x1) {
        unsigned h = (l * 2654435761u) >> 21;
        int idx = -1;
        for (int pr = 0; pr < 32; ++pr) {
            unsigned j = (h + pr) & (SLOTS - 1);
            unsigned k = hk[j];
            if (k == l) { idx = (int)j; break; }
            if (k == 0u) {
                unsigned old = atomicCAS(&hk[j], 0u, l);
                if (old == 0u || old == l) { idx = (int)j; break; }
            }
        }
        if (idx >= 0) {
            atomicAdd(&hc[idx], cnt);
            atomicMax(&sx0r[idx], 511u - x0); atomicMax(&sx1[idx], x1);
            atomicMax(&sy0r[idx], 511u - y);  atomicMax(&sy1[idx], y);
        } else {                                  // rare LDS overflow
            unsigned g = gfind_ins(gki, l, dli, dci);
            atomicAdd(&gci[g], cnt);
            atomicMax(&gx0i[g], 511u - x0); atomicMax(&gx1i[g], x1);
            atomicMax(&gy0i[g], 511u - y);  atomicMax(&gy1i[g], y);
        }
    };

    // thread t owns int4 indices [t*8, t*8+8) = 32 consecutive px of row y
    const int4* lp = (const int4*)(lab + (size_t)img * HW + rb * IW);
    const unsigned xc = (unsigned)((t & 15) * 32);
    unsigned cur = 0, cnt = 0, rx0 = 0, rx1 = 0;
#pragma unroll 1
    for (int j = 0; j < 8; ++j) {
        int4 v = lp[t * 8 + j];
        unsigned xb = xc + (unsigned)(j * 4);
#define STEP(L, E)                                                             \
        {                                                                      \
            unsigned l_ = (unsigned)(L);                                       \
            if (l_ != cur) {                                                   \
                if (cur) upd(cur, cnt, rx0, rx1);                              \
                cur = l_; cnt = 0; rx0 = xb + (E);                             \
            }                                                                  \
            if (cur) { cnt++; rx1 = xb + (E); }                                \
        }
        STEP(v.x, 0u) STEP(v.y, 1u) STEP(v.z, 2u) STEP(v.w, 3u)
#undef STEP
    }
    if (cur) upd(cur, cnt, rx0, rx1);
    __syncthreads();

    for (int i = t; i < SLOTS; i += 256) {
        unsigned k = hk[i];
        if (!k) continue;
        unsigned g = gfind_ins(gki, k, dli, dci);
        atomicAdd(&gci[g], hc[i]);
        atomicMax(&gx0i[g], sx0r[i]); atomicMax(&gx1i[g], sx1[i]);
        atomicMax(&gy0i[g], sy0r[i]); atomicMax(&gy1i[g], sy1[i]);
    }
}

// ---------------- 4. exact top-100: dense-list load + cached-argmax ----------
// key = ((count<<19)|(HW-label))<<15 | slot  (count desc, label asc ==
// lax.top_k tie order; slot gathers bbox; keys unique).
__global__ __launch_bounds__(256) void topk(const unsigned* __restrict__ gk,
                                            const unsigned* __restrict__ gcnt,
                                            const unsigned* __restrict__ dlist,
                                            const unsigned* __restrict__ dcount,
                                            unsigned* __restrict__ rank_count,
                                            unsigned* __restrict__ rank_slot) {
    __shared__ unsigned long long keys[CAP];
    __shared__ unsigned long long wred[4];
    const int img = blockIdx.x;
    const int t = threadIdx.x;
    const int lane = t & 63, wid = t >> 6;
    for (int i = t; i < CAP; i += 256) keys[i] = 0;
    __syncthreads();

    unsigned nd = dcount[img];
    if (nd > CAP) nd = CAP;
    const unsigned* gki = gk + (size_t)img * GH;
    const unsigned* gci = gcnt + (size_t)img * GH;
    const unsigned* dli = dlist + (size_t)img * DCAP;
    for (unsigned i = t; i < nd; i += 256) {
        unsigned slot = dli[i];
        unsigned lb = gki[slot];
        unsigned c = gci[slot];
        keys[i] = ((((unsigned long long)c << 19) | (unsigned)(HW - lb)) << 15)
                  | slot;
    }
    __syncthreads();

    unsigned long long maxv = 0; int maxi = -1;
    for (int i = t; i < CAP; i += 256) {
        unsigned long long k = keys[i];
        if (k > maxv) { maxv = k; maxi = i; }
    }

    for (int r = 0; r < MAXD; ++r) {
        unsigned long long m = maxv;
        for (int s = 1; s < 64; s <<= 1) {
            unsigned long long o = (unsigned long long)__shfl_xor((long long)m, s, 64);
            if (o > m) m = o;
        }
        if (lane == 0) wred[wid] = m;
        __syncthreads();
        unsigned long long w = wred[0];
        if (wred[1] > w) w = wred[1];
        if (wred[2] > w) w = wred[2];
        if (wred[3] > w) w = wred[3];
        if (w != 0ull && maxv == w) {            // unique owner (keys unique)
            keys[maxi] = 0;
            rank_count[img * MAXD + r] = (unsigned)(w >> 34);
            rank_slot[img * MAXD + r]  = (unsigned)(w & 32767ull);
            maxv = 0; maxi = -1;
            for (int i = t; i < CAP; i += 256) {
                unsigned long long k = keys[i];
                if (k > maxv) { maxv = k; maxi = i; }
            }
        }
        if (w == 0ull && t == 0) {
            rank_count[img * MAXD + r] = 0;
            rank_slot[img * MAXD + r] = 0;
        }
        __syncthreads();
    }
}

// ---------------- 5. finalize: gather [xmin,ymin,xmax,ymax] or zeros ---------
__global__ __launch_bounds__(256) void final_out(const unsigned* __restrict__ rank_count,
                                                 const unsigned* __restrict__ rank_slot,
                                                 const unsigned* __restrict__ gx0r,
                                                 const unsigned* __restrict__ gx1,
                                                 const unsigned* __restrict__ gy0r,
                                                 const unsigned* __restrict__ gy1,
                                                 float* __restrict__ out) {
    int id = blockIdx.x * 256 + threadIdx.x;
    if (id >= NIMG * MAXD) return;
    unsigned c = rank_count[id];
    float4 b = make_float4(0.f, 0.f, 0.f, 0.f);
    if (c) {
        int img = id / MAXD;
        size_t g = (size_t)img * GH + rank_slot[id];
        b = make_float4((float)(511u - gx0r[g]), (float)(511u - gy0r[g]),
                        (float)gx1[g], (float)gy1[g]);
    }
    reinterpret_cast<float4*>(out)[id] = b;
}

// ---------------- launch ----------------
extern "C" void kernel_launch(void* const* d_in, const int* in_sizes, int n_in,
                              void* d_out, int out_size, void* d_ws, size_t ws_size,
                              hipStream_t stream) {
    (void)in_sizes; (void)n_in; (void)out_size; (void)ws_size;
    const float* img = (const float*)d_in[0];
    char* ws = (char*)d_ws;

    int* labA = (int*)ws;
    int* labB = (int*)(ws + OFF_LABB);
    // hash region aliases labB (dead after EVEN pass count: labels end in labA)
    char* hb = ws + OFF_LABB;
    unsigned* gk   = (unsigned*)hb;                       // +0..1MB
    unsigned* gcnt = (unsigned*)(hb + 1048576ull);        // +1..2MB
    unsigned* gx1  = (unsigned*)(hb + 2097152ull);        // +2..3MB
    unsigned* gy1  = (unsigned*)(hb + 3145728ull);        // +3..4MB
    unsigned* gx0r = (unsigned*)(hb + 4194304ull);        // +4..5MB  max(511-x)
    unsigned* gy0r = (unsigned*)(hb + 5242880ull);        // +5..6MB  max(511-y)
    unsigned* dcount = (unsigned*)(hb + 6291456ull);      // +6MB..+4K
    unsigned* dlist = (unsigned*)(hb + 6295552ull);       // 1MB
    unsigned* rank_count = (unsigned*)(hb + 8388608ull);
    unsigned* rank_slot  = (unsigned*)(hb + 8388608ull + 16384ull);
    float* out = (float*)d_out;

    init_labels<<<2048, 256, 0, stream>>>((const float4*)img, (int4*)labA);

    // 20 passes x 10 iterations = exactly 200 masked maxpool iterations
    dim3 pg(NTX, NTY, NIMG);
    const int* pin = labA; int* pout = labB;
    for (int p = 0; p < NPASS; ++p) {
        prop_pass<<<pg, 64, 0, stream>>>(pin, pout);
        int* tmp = (int*)pin; pin = pout; pout = tmp;
    }
    // NPASS even -> final labels in labA; labB region now free for the hash

    hipMemsetAsync(gk, 0, 6291456ull + 4096ull, stream);  // all hash arrays + dcount

    stat_pass<<<dim3(32, NIMG), 256, 0, stream>>>(pin, gk, gcnt, gx0r, gx1, gy0r, gy1,
                                                  dlist, dcount);
    topk<<<NIMG, 256, 0, stream>>>(gk, gcnt, dlist, dcount, rank_count, rank_slot);
    final_out<<<(NIMG * MAXD + 255) / 256, 256, 0, stream>>>(rank_count, rank_slot,
                                                             gx0r, gx1, gy0r, gy1, out);
}